// Round 16
// baseline (469.904 us; speedup 1.0000x reference)
//
#include <hip/hip_runtime.h>

// HeteroGNN fused implementation, round 16.
// Algebra: new = relu( S @ W1 + deg.*(x @ W2) + x @ W3 + deg.*bmp + bu )
// Round-16: layer-1 aggregation switched to edge-parallel fp32 atomics into
// L2-resident S8 (1.6MB/rel) -- r15 showed the CSR-gather gemm_l1_f was
// structurally latency-bound at 48us regardless of micro-fixes. gemm_l1 is
// now pure streaming; node-side CSR deleted (bucket passes link-only,
// bucket_deg2 replaced by a 1-block gcount scan). deg kept as int.

#define H 128
#define NN 50000
#define NL 50000
#define NE 400000
#define NG 64
#define FR 8
#define NB 49          // dst buckets (dst >> 10)
#define BCAP 12288     // entries per bucket (expected ~8163)
#define TSTR 136       // LDS row stride (bf16 elems), layer-2 tile
#define TROWS 32       // layer-2 tile rows

typedef __attribute__((ext_vector_type(8))) short bf16x8;
typedef __attribute__((ext_vector_type(4))) float f32x4;
typedef unsigned short ushort_t;
typedef unsigned int uint_t;

__device__ __forceinline__ ushort_t f2bf(float f) {
    union { float f; unsigned u; } v; v.f = f;
    unsigned r = v.u + 0x7FFFu + ((v.u >> 16) & 1u);   // RNE
    return (ushort_t)(r >> 16);
}
__device__ __forceinline__ float bf2f(ushort_t u) {
    union { unsigned u; float f; } v; v.u = ((unsigned)u) << 16; return v.f;
}
__device__ __forceinline__ void addpk8(float* a, uint4 u) {
    const unsigned* w = (const unsigned*)&u;
#pragma unroll
    for (int q = 0; q < 4; ++q) {
        union { unsigned u; float f; } lo, hi;
        lo.u = w[q] << 16;
        hi.u = w[q] & 0xFFFF0000u;
        a[q * 2 + 0] += lo.f;
        a[q * 2 + 1] += hi.f;
    }
}
__device__ __forceinline__ uint2 pk4(const float* a) {
    uint2 r;
    r.x = (unsigned)f2bf(a[0]) | ((unsigned)f2bf(a[1]) << 16);
    r.y = (unsigned)f2bf(a[2]) | ((unsigned)f2bf(a[3]) << 16);
    return r;
}

// ---------------- weight fusion (+ bf16 per-tile layout for layer-2 link) ----------------
__global__ void precompute_w(const float* __restrict__ Wm_nl, const float* __restrict__ bm_nl,
                             const float* __restrict__ Wu_nl,
                             const float* __restrict__ Wm_ln, const float* __restrict__ bm_ln,
                             const float* __restrict__ Wu_ln,
                             float* __restrict__ Wstack, float* __restrict__ bmp,
                             ushort_t* __restrict__ WbLin) {
    int idx = blockIdx.x * blockDim.x + threadIdx.x;
    const int per = 384 * H + H;
    int c = idx / per, r = idx % per;
    if (c >= 3) return;   // combo 3 (layer-2 node update) is dead code
    int l = c >> 1, rel = c & 1;
    const float* Wm = (rel ? Wm_ln : Wm_nl) + l * 256 * H;
    const float* Wu = (rel ? Wu_ln : Wu_nl) + l * 256 * H;
    const float* bm = (rel ? bm_ln : bm_nl) + l * H;
    float* Ws = Wstack + c * 384 * H;
    if (r < 384 * H) {
        int t = r / H, j = r % H;
        float val;
        if (t < 256) {
            float acc = 0.f;
            for (int k = 0; k < H; ++k) acc += Wm[t * H + k] * Wu[k * H + j];
            val = acc;
        } else {
            val = Wu[(t - 128) * H + j];
        }
        Ws[t * H + j] = val;
        if (c == 2) {
            WbLin[(size_t)(t >> 5) * 4096 + j * 32 + (t & 31)] = f2bf(val);
        }
    } else {
        int j = r - 384 * H;
        float acc = 0.f;
        for (int k = 0; k < H; ++k) acc += bm[k] * Wu[k * H + j];
        bmp[c * H + j] = acc;
    }
}

// ---------------- layer-1 aggregation: edge-parallel atomics into L2-resident S8 ----------------
__launch_bounds__(256)
__global__ void s8_deg(const int* __restrict__ nl, const int* __restrict__ ln,
                       const float* __restrict__ x_node, const float* __restrict__ x_link,
                       float* __restrict__ S8l, float* __restrict__ S8n,
                       int* __restrict__ idl, int* __restrict__ idn) {
    int rel = blockIdx.y;
    const int* edge = rel ? ln : nl;
    const float* Xr = rel ? x_link : x_node;   // src-type raw features
    float* S8 = rel ? S8n : S8l;
    int* ideg = rel ? idn : idl;
    int e = blockIdx.x * 256 + threadIdx.x;
    if (e >= NE) return;
    int src = edge[e], dst = edge[NE + e];
    float4 a0 = *(const float4*)(Xr + (size_t)src * FR);
    float4 a1 = *(const float4*)(Xr + (size_t)src * FR + 4);
    float* p = S8 + (size_t)dst * FR;
    atomicAdd(p + 0, a0.x); atomicAdd(p + 1, a0.y);
    atomicAdd(p + 2, a0.z); atomicAdd(p + 3, a0.w);
    atomicAdd(p + 4, a1.x); atomicAdd(p + 5, a1.y);
    atomicAdd(p + 6, a1.z); atomicAdd(p + 7, a1.w);
    atomicAdd(&ideg[dst], 1);
}

// ---------------- link-side bucket scatter (for layer-2 CSR only) ----------------
__launch_bounds__(256)
__global__ void bucket_scatter_l(const int* __restrict__ nl,
                                 uint_t* __restrict__ bbuf, int* __restrict__ gcount) {
    __shared__ int hist[NB], base[NB], cur[NB];
    int tid = threadIdx.x;
    if (tid < NB) hist[tid] = 0;
    __syncthreads();
    int e0 = blockIdx.x * 2048 + tid;
    int src[8], dst[8];
#pragma unroll
    for (int i = 0; i < 8; ++i) {
        int e = e0 + i * 256;
        if (e < NE) {
            src[i] = nl[e];
            dst[i] = nl[NE + e];
            atomicAdd(&hist[dst[i] >> 10], 1);
        } else dst[i] = -1;
    }
    __syncthreads();
    if (tid < NB) { base[tid] = atomicAdd(&gcount[tid], hist[tid]); cur[tid] = 0; }
    __syncthreads();
#pragma unroll
    for (int i = 0; i < 8; ++i) {
        if (dst[i] >= 0) {
            int b = dst[i] >> 10;
            int p = base[b] + atomicAdd(&cur[b], 1);
            bbuf[(size_t)b * BCAP + p] = (uint_t)src[i] | ((uint_t)(dst[i] & 1023) << 16);
        }
    }
}

// ---------------- gcount exclusive scan (1 block) ----------------
__global__ void gscan(const int* __restrict__ gcount, int* __restrict__ bbase) {
    __shared__ int sh[64];
    int tid = threadIdx.x;
    int v0 = (tid < NB) ? gcount[tid] : 0;
    sh[tid] = v0;
    __syncthreads();
    for (int d = 1; d < 64; d <<= 1) {
        int vv = (tid >= d) ? sh[tid - d] : 0;
        __syncthreads();
        sh[tid] += vv;
        __syncthreads();
    }
    if (tid < NB) bbase[tid] = sh[tid] - v0;
}

// ---------------- link-only offset scan + CSR fill ----------------
__launch_bounds__(256)
__global__ void scan_fill_l(const int* __restrict__ idl, const int* __restrict__ bbase,
                            int* __restrict__ offL,
                            const uint_t* __restrict__ bbuf, const int* __restrict__ gcount,
                            int* __restrict__ adjL) {
    int blk = blockIdx.x;
    const uint_t* bb = bbuf + (size_t)blk * BCAP;
    int n = gcount[blk];

    __shared__ int part[256];
    __shared__ int lcur[1024];
    int tid = threadIdx.x;
    int base = blk * 1024 + tid * 4;
    int d4[4]; int s = 0;
#pragma unroll
    for (int i = 0; i < 4; ++i) {
        int idx = base + i;
        d4[i] = (idx < NL) ? idl[idx] : 0;
        s += d4[i];
    }
    part[tid] = s;
    __syncthreads();
    for (int d = 1; d < 256; d <<= 1) {
        int v = (tid >= d) ? part[tid - d] : 0;
        __syncthreads();
        part[tid] += v;
        __syncthreads();
    }
    int run = bbase[blk] + part[tid] - s;
#pragma unroll
    for (int i = 0; i < 4; ++i) {
        int idx = base + i;
        lcur[tid * 4 + i] = run;
        if (idx < NL) {
            offL[idx] = run;
            run += d4[i];
            if (idx == NL - 1) offL[NL] = run;
        }
    }
    __syncthreads();
    for (int i = tid; i < n; i += 256) {
        uint_t v = bb[i];
        int p = atomicAdd(&lcur[v >> 16], 1);
        adjL[p] = (int)(v & 0xFFFFu);
    }
}

// ---------------- layer-1: pure streaming GEMM (K=24), bf16 out ----------------
__launch_bounds__(256)
__global__ void gemm_l1(const float* __restrict__ S8l, const float* __restrict__ S8n,
                        const float* __restrict__ x_node, const float* __restrict__ x_link,
                        const int* __restrict__ idl, const int* __restrict__ idn,
                        const float* __restrict__ Wstack, const float* __restrict__ bmpAll,
                        const float* __restrict__ bu_nl, const float* __restrict__ bu_ln,
                        ushort_t* __restrict__ outl, ushort_t* __restrict__ outn) {
    int rel = blockIdx.y;
    const float* S8  = rel ? S8n : S8l;
    const float* Xo  = rel ? x_node : x_link;   // own raw features
    const int* ideg = rel ? idn : idl;
    const float* Ws  = Wstack + (size_t)rel * 384 * H;
    const float* bmp = bmpAll + rel * H;
    const float* bu  = rel ? bu_ln : bu_nl;
    ushort_t* Out = rel ? outn : outl;

    __shared__ float Wl[24][H];
    __shared__ float bf2s[2][H];
    int tid = threadIdx.x;
    for (int p = tid; p < 24 * H; p += 256) {
        int kk = p >> 7, c = p & 127;
        int srcrow = (kk >> 3) * 128 + (kk & 7);
        Wl[kk][c] = Ws[srcrow * H + c];
    }
    if (tid < 128) { bf2s[0][tid] = bmp[tid]; bf2s[1][tid] = bu[tid]; }
    __syncthreads();

    int rl = tid >> 4, t16 = tid & 15;
    int row = blockIdx.x * 16 + rl;              // grid 3125 -> exact
    float d = (float)ideg[row];
    float a[16];
    *(float4*)(a)      = *(const float4*)(S8 + (size_t)row * FR);
    *(float4*)(a + 4)  = *(const float4*)(S8 + (size_t)row * FR + 4);
    *(float4*)(a + 8)  = *(const float4*)(Xo + (size_t)row * FR);
    *(float4*)(a + 12) = *(const float4*)(Xo + (size_t)row * FR + 4);

    int c0 = t16 * 4, c1 = 64 + t16 * 4;
    float acc[8] = {};
#pragma unroll
    for (int k = 0; k < 8; ++k) {
        float4 w0 = *(const float4*)(&Wl[k][c0]);
        float4 w1 = *(const float4*)(&Wl[k][c1]);
        float av = a[k];
        acc[0] += av * w0.x; acc[1] += av * w0.y; acc[2] += av * w0.z; acc[3] += av * w0.w;
        acc[4] += av * w1.x; acc[5] += av * w1.y; acc[6] += av * w1.z; acc[7] += av * w1.w;
    }
#pragma unroll
    for (int k = 0; k < 8; ++k) {
        float4 w0 = *(const float4*)(&Wl[8 + k][c0]);
        float4 w1 = *(const float4*)(&Wl[8 + k][c1]);
        float av = d * a[8 + k];
        acc[0] += av * w0.x; acc[1] += av * w0.y; acc[2] += av * w0.z; acc[3] += av * w0.w;
        acc[4] += av * w1.x; acc[5] += av * w1.y; acc[6] += av * w1.z; acc[7] += av * w1.w;
    }
#pragma unroll
    for (int k = 0; k < 8; ++k) {
        float4 w0 = *(const float4*)(&Wl[16 + k][c0]);
        float4 w1 = *(const float4*)(&Wl[16 + k][c1]);
        float av = a[8 + k];
        acc[0] += av * w0.x; acc[1] += av * w0.y; acc[2] += av * w0.z; acc[3] += av * w0.w;
        acc[4] += av * w1.x; acc[5] += av * w1.y; acc[6] += av * w1.z; acc[7] += av * w1.w;
    }

    float o0[4], o1[4];
#pragma unroll
    for (int j = 0; j < 4; ++j) {
        o0[j] = fmaxf(acc[j]     + d * bf2s[0][c0 + j] + bf2s[1][c0 + j], 0.f);
        o1[j] = fmaxf(acc[j + 4] + d * bf2s[0][c1 + j] + bf2s[1][c1 + j], 0.f);
    }
    *(uint2*)(Out + (size_t)row * H + c0) = pk4(o0);
    *(uint2*)(Out + (size_t)row * H + c1) = pk4(o1);
}

// ---------------- layer-2: fused gather + MFMA GEMM + pooled epilogue (link only) ----------------
__launch_bounds__(256)
__global__ void gemm_mfma_pool(const int* __restrict__ offL, const int* __restrict__ adjL,
                               const ushort_t* __restrict__ xlb, const ushort_t* __restrict__ xnb,
                               const int* __restrict__ idl,
                               const ushort_t* __restrict__ WbLin, const float* __restrict__ bmpAll,
                               const float* __restrict__ bu_nl,
                               const int* __restrict__ batch, float* __restrict__ sums, int M) {
    const int* off = offL;
    const int* adj = adjL;
    const ushort_t* Xg = xnb;
    const ushort_t* Xo = xlb;
    const ushort_t* Wb = WbLin;
    const float* bmp = bmpAll + 2 * H;
    const float* bu  = bu_nl + H;

    __shared__ ushort_t T[TROWS * TSTR];   // 8.7 KB

    int tid = threadIdx.x;
    int lane = tid & 63;
    int wave = tid >> 6;
    int m0 = blockIdx.x * TROWS;
    int lrow = lane & 15, lg = lane >> 4;

    int trow = tid >> 3, chunk = tid & 7;
    int grow = m0 + trow;
    bool vr = grow < M;
    int cbase = chunk * 16;

    // ---- phase A: gather S (fp32 accum, 2-neighbor unroll) -> bf16 tile ----
    {
        float a[16];
#pragma unroll
        for (int j = 0; j < 16; ++j) a[j] = 0.f;
        if (vr) {
            int beg = off[grow], end = off[grow + 1];
            int i = beg;
            for (; i + 1 < end; i += 2) {
                const uint4* p0 = (const uint4*)(Xg + (size_t)adj[i] * H + cbase);
                const uint4* p1 = (const uint4*)(Xg + (size_t)adj[i + 1] * H + cbase);
                uint4 u0 = p0[0], u1 = p0[1];
                uint4 v0 = p1[0], v1 = p1[1];
                addpk8(a, u0); addpk8(a + 8, u1);
                addpk8(a, v0); addpk8(a + 8, v1);
            }
            if (i < end) {
                const uint4* p0 = (const uint4*)(Xg + (size_t)adj[i] * H + cbase);
                addpk8(a, p0[0]); addpk8(a + 8, p0[1]);
            }
        }
        uint4* dst = (uint4*)&T[trow * TSTR + cbase];
        uint4 w0, w1;
        unsigned* q0 = (unsigned*)&w0; unsigned* q1 = (unsigned*)&w1;
#pragma unroll
        for (int q = 0; q < 4; ++q) {
            q0[q] = (unsigned)f2bf(a[q * 2]) | ((unsigned)f2bf(a[q * 2 + 1]) << 16);
            q1[q] = (unsigned)f2bf(a[8 + q * 2]) | ((unsigned)f2bf(a[8 + q * 2 + 1]) << 16);
        }
        dst[0] = w0; dst[1] = w1;
    }

    f32x4 acc[2][2];
#pragma unroll
    for (int i = 0; i < 2; ++i)
#pragma unroll
        for (int j = 0; j < 2; ++j)
            acc[i][j] = (f32x4){0.f, 0.f, 0.f, 0.f};

    __syncthreads();
#pragma unroll
    for (int kk = 0; kk < 4; ++kk) {
        bf16x8 af[2], bfv[2];
#pragma unroll
        for (int mf = 0; mf < 2; ++mf)
            af[mf] = *(const bf16x8*)&T[(mf * 16 + lrow) * TSTR + kk * 32 + lg * 8];
#pragma unroll
        for (int nf = 0; nf < 2; ++nf)
            bfv[nf] = *(const bf16x8*)(Wb + (size_t)kk * 4096
                        + (wave * 32 + nf * 16 + lrow) * 32 + lg * 8);
#pragma unroll
        for (int mf = 0; mf < 2; ++mf)
#pragma unroll
            for (int nf = 0; nf < 2; ++nf)
                acc[mf][nf] = __builtin_amdgcn_mfma_f32_16x16x32_bf16(
                    af[mf], bfv[nf], acc[mf][nf], 0, 0, 0);
    }
    __syncthreads();

    // ---- phase B: own x row (stash) -> deg-scaled tile ----
    uint4 xs0, xs1;
    {
        if (vr) {
            const uint4* p = (const uint4*)(Xo + (size_t)grow * H + cbase);
            xs0 = p[0]; xs1 = p[1];
        } else {
            xs0 = xs1 = make_uint4(0u, 0u, 0u, 0u);
        }
        float dr = vr ? (float)idl[grow] : 0.f;
        uint4 w0 = xs0, w1 = xs1;
        unsigned* wp0 = (unsigned*)&w0;
        unsigned* wp1 = (unsigned*)&w1;
#pragma unroll
        for (int q = 0; q < 4; ++q) {
            float v0 = dr * bf2f((ushort_t)(wp0[q] & 0xFFFF));
            float v1 = dr * bf2f((ushort_t)(wp0[q] >> 16));
            wp0[q] = (unsigned)f2bf(v0) | ((unsigned)f2bf(v1) << 16);
            float v2 = dr * bf2f((ushort_t)(wp1[q] & 0xFFFF));
            float v3 = dr * bf2f((ushort_t)(wp1[q] >> 16));
            wp1[q] = (unsigned)f2bf(v2) | ((unsigned)f2bf(v3) << 16);
        }
        uint4* dst = (uint4*)&T[trow * TSTR + cbase];
        dst[0] = w0; dst[1] = w1;
    }
    __syncthreads();
#pragma unroll
    for (int kk = 0; kk < 4; ++kk) {
        bf16x8 af[2], bfv[2];
#pragma unroll
        for (int mf = 0; mf < 2; ++mf)
            af[mf] = *(const bf16x8*)&T[(mf * 16 + lrow) * TSTR + kk * 32 + lg * 8];
#pragma unroll
        for (int nf = 0; nf < 2; ++nf)
            bfv[nf] = *(const bf16x8*)(Wb + (size_t)(4 + kk) * 4096
                        + (wave * 32 + nf * 16 + lrow) * 32 + lg * 8);
#pragma unroll
        for (int mf = 0; mf < 2; ++mf)
#pragma unroll
            for (int nf = 0; nf < 2; ++nf)
                acc[mf][nf] = __builtin_amdgcn_mfma_f32_16x16x32_bf16(
                    af[mf], bfv[nf], acc[mf][nf], 0, 0, 0);
    }
    __syncthreads();

    // ---- phase C: unscaled x tile (from stash) ----
    {
        uint4* dst = (uint4*)&T[trow * TSTR + cbase];
        dst[0] = xs0; dst[1] = xs1;
    }
    __syncthreads();
#pragma unroll
    for (int kk = 0; kk < 4; ++kk) {
        bf16x8 af[2], bfv[2];
#pragma unroll
        for (int mf = 0; mf < 2; ++mf)
            af[mf] = *(const bf16x8*)&T[(mf * 16 + lrow) * TSTR + kk * 32 + lg * 8];
#pragma unroll
        for (int nf = 0; nf < 2; ++nf)
            bfv[nf] = *(const bf16x8*)(Wb + (size_t)(8 + kk) * 4096
                        + (wave * 32 + nf * 16 + lrow) * 32 + lg * 8);
#pragma unroll
        for (int mf = 0; mf < 2; ++mf)
#pragma unroll
            for (int nf = 0; nf < 2; ++nf)
                acc[mf][nf] = __builtin_amdgcn_mfma_f32_16x16x32_bf16(
                    af[mf], bfv[nf], acc[mf][nf], 0, 0, 0);
    }

    // ---- epilogue: bias + relu + fused mean-pool ----
    float bmpv[2], buv[2];
#pragma unroll
    for (int nf = 0; nf < 2; ++nf) {
        int col = wave * 32 + nf * 16 + lrow;
        bmpv[nf] = bmp[col];
        buv[nf] = bu[col];
    }
    int lastrow = min(m0 + TROWS, M) - 1;
    int g0 = batch[m0];
    int g1 = batch[lastrow];
    if (g0 == g1) {
        float ps0 = 0.f, ps1 = 0.f;
#pragma unroll
        for (int mf = 0; mf < 2; ++mf) {
#pragma unroll
            for (int r = 0; r < 4; ++r) {
                int row = m0 + mf * 16 + lg * 4 + r;
                if (row < M) {
                    float d = (float)idl[row];
                    ps0 += fmaxf(acc[mf][0][r] + d * bmpv[0] + buv[0], 0.f);
                    ps1 += fmaxf(acc[mf][1][r] + d * bmpv[1] + buv[1], 0.f);
                }
            }
        }
        ps0 += __shfl_xor(ps0, 16); ps0 += __shfl_xor(ps0, 32);
        ps1 += __shfl_xor(ps1, 16); ps1 += __shfl_xor(ps1, 32);
        if (lg == 0) {
            atomicAdd(&sums[g0 * H + wave * 32 + lrow], ps0);
            atomicAdd(&sums[g0 * H + wave * 32 + 16 + lrow], ps1);
        }
    } else {
#pragma unroll
        for (int mf = 0; mf < 2; ++mf) {
#pragma unroll
            for (int r = 0; r < 4; ++r) {
                int row = m0 + mf * 16 + lg * 4 + r;
                if (row < M) {
                    float d = (float)idl[row];
                    int g = batch[row];
                    float v0 = fmaxf(acc[mf][0][r] + d * bmpv[0] + buv[0], 0.f);
                    float v1 = fmaxf(acc[mf][1][r] + d * bmpv[1] + buv[1], 0.f);
                    atomicAdd(&sums[g * H + wave * 32 + lrow], v0);
                    atomicAdd(&sums[g * H + wave * 32 + 16 + lrow], v1);
                }
            }
        }
    }
}

// ---------------- pool finalize (counts via binary search) ----------------
__global__ void pool_final(const float* __restrict__ sums, const int* __restrict__ batch,
                           float* __restrict__ out) {
    int idx = blockIdx.x * blockDim.x + threadIdx.x;
    int g = idx / H;
    int lo = 0, hi = NL;
    while (lo < hi) { int mid = (lo + hi) >> 1; if (batch[mid] < g) lo = mid + 1; else hi = mid; }
    int first = lo;
    lo = 0; hi = NL;
    while (lo < hi) { int mid = (lo + hi) >> 1; if (batch[mid] < g + 1) lo = mid + 1; else hi = mid; }
    float cnt = (float)(lo - first);
    out[idx] = sums[idx] / fmaxf(cnt, 1.f);
}

static inline size_t rup(size_t n) { return (n + 15) & ~(size_t)15; }

extern "C" void kernel_launch(void* const* d_in, const int* in_sizes, int n_in,
                              void* d_out, int out_size, void* d_ws, size_t ws_size,
                              hipStream_t stream) {
    const float* x_node = (const float*)d_in[0];
    const float* x_link = (const float*)d_in[1];
    const float* Wm_nl  = (const float*)d_in[2];
    const float* bm_nl  = (const float*)d_in[3];
    const float* Wu_nl  = (const float*)d_in[4];
    const float* bu_nl  = (const float*)d_in[5];
    const float* Wm_ln  = (const float*)d_in[6];
    const float* bm_ln  = (const float*)d_in[7];
    const float* Wu_ln  = (const float*)d_in[8];
    const float* bu_ln  = (const float*)d_in[9];
    const int* nl_edge  = (const int*)d_in[10];
    const int* ln_edge  = (const int*)d_in[11];
    const int* batch_link = (const int*)d_in[12];
    (void)in_sizes; (void)n_in; (void)out_size; (void)ws_size;

    char* wsb = (char*)d_ws;
    size_t o = 0;
    auto alloc = [&](size_t elems) { void* p = wsb + o * 4; o += rup(elems); return p; };
    ushort_t* xnb  = (ushort_t*)alloc((size_t)NN * H / 2);
    ushort_t* xlb  = (ushort_t*)alloc((size_t)NL * H / 2);
    // contiguous zero region: S8l, S8n, idl, idn (3.6 MB total)
    float* S8l   = (float*)alloc((size_t)NL * FR);
    float* S8n   = (float*)alloc((size_t)NN * FR);
    int*   idl   = (int*)alloc(NL);
    int*   idn   = (int*)alloc(NN);
    int*   offL  = (int*)alloc(NL + 1);
    int*   adjL  = (int*)alloc(NE);
    float* Wstack= (float*)alloc(3L * 384 * H);
    float* bmp   = (float*)alloc(4 * H);
    ushort_t* WbLin = (ushort_t*)alloc(12 * 4096 / 2);
    uint_t* bbuf  = (uint_t*)alloc((size_t)NB * BCAP);
    int*   bbase = (int*)alloc(NB);
    // contiguous zero region: sums, gcount
    float* sums  = (float*)alloc(NG * H);    // 8192 (16-aligned)
    int*   gcount= (int*)alloc(NB);

    hipMemsetAsync(S8l, 0, ((size_t)NL * FR + NN * FR + rup(NL) + NN) * 4, stream);
    hipMemsetAsync(sums, 0, ((size_t)NG * H + rup(NB)) * 4, stream);

    precompute_w<<<(4 * (384 * H + H) + 255) / 256, 256, 0, stream>>>(
        Wm_nl, bm_nl, Wu_nl, Wm_ln, bm_ln, Wu_ln, Wstack, bmp, WbLin);

    // ---- layer-1 aggregation (edge-parallel atomics) + link CSR build ----
    s8_deg<<<dim3((NE + 255) / 256, 2), 256, 0, stream>>>(
        nl_edge, ln_edge, x_node, x_link, S8l, S8n, idl, idn);
    bucket_scatter_l<<<(NE + 2047) / 2048, 256, 0, stream>>>(nl_edge, bbuf, gcount);
    gscan<<<1, 64, 0, stream>>>(gcount, bbase);
    scan_fill_l<<<NB, 256, 0, stream>>>(idl, bbase, offL, bbuf, gcount, adjL);

    // ---- layer 1 (pure streaming GEMM, both relations) ----
    gemm_l1<<<dim3(NL / 16, 2), 256, 0, stream>>>(
        S8l, S8n, x_node, x_link, idl, idn,
        Wstack, bmp, bu_nl, bu_ln, xlb, xnb);

    // ---- layer 2 (link only) + fused pool ----
    gemm_mfma_pool<<<(NL + TROWS - 1) / TROWS, 256, 0, stream>>>(
        offL, adjL, xlb, xnb, idl, WbLin, bmp, bu_nl,
        batch_link, sums, NL);

    pool_final<<<(NG * H) / 256, 256, 0, stream>>>(sums, batch_link, (float*)d_out);
}

// Round 17
// 150.302 us; speedup vs baseline: 3.1264x; 3.1264x over previous
//
#include <hip/hip_runtime.h>

// HeteroGNN fused implementation, round 17.
// Algebra: new = relu( S @ W1 + deg.*(x @ W2) + x @ W3 + deg.*bmp + bu )
// Round-17: layer-1 aggregation = r13's LDS-bucket accumulation with 8x finer
// buckets (391 buckets x 128 dsts, grid 782 vs r13's 98 -- r13's 90us was
// grid starvation at 4% occupancy, not the mechanism). Global fp32 atomics
// are confirmed write-through (r1: 800MB, r16: 224MB) and永 banned.
// Downstream identical to r16: streaming gemm_l1, link-only CSR,
// gemm_mfma_pool with fused pool, pool_final.

#define H 128
#define NN 50000
#define NL 50000
#define NE 400000
#define NG 64
#define FR 8
#define NB2 391        // buckets of 128 dsts (dst >> 7)
#define BCAP2 1536     // entries per bucket (expected ~1024, sigma 32)
#define TSTR 136       // LDS row stride (bf16 elems), layer-2 tile
#define TROWS 32       // layer-2 tile rows

typedef __attribute__((ext_vector_type(8))) short bf16x8;
typedef __attribute__((ext_vector_type(4))) float f32x4;
typedef unsigned short ushort_t;
typedef unsigned int uint_t;

__device__ __forceinline__ ushort_t f2bf(float f) {
    union { float f; unsigned u; } v; v.f = f;
    unsigned r = v.u + 0x7FFFu + ((v.u >> 16) & 1u);   // RNE
    return (ushort_t)(r >> 16);
}
__device__ __forceinline__ float bf2f(ushort_t u) {
    union { unsigned u; float f; } v; v.u = ((unsigned)u) << 16; return v.f;
}
__device__ __forceinline__ void addpk8(float* a, uint4 u) {
    const unsigned* w = (const unsigned*)&u;
#pragma unroll
    for (int q = 0; q < 4; ++q) {
        union { unsigned u; float f; } lo, hi;
        lo.u = w[q] << 16;
        hi.u = w[q] & 0xFFFF0000u;
        a[q * 2 + 0] += lo.f;
        a[q * 2 + 1] += hi.f;
    }
}
__device__ __forceinline__ uint2 pk4(const float* a) {
    uint2 r;
    r.x = (unsigned)f2bf(a[0]) | ((unsigned)f2bf(a[1]) << 16);
    r.y = (unsigned)f2bf(a[2]) | ((unsigned)f2bf(a[3]) << 16);
    return r;
}

// ---------------- weight fusion (+ bf16 per-tile layout for layer-2 link) ----------------
__global__ void precompute_w(const float* __restrict__ Wm_nl, const float* __restrict__ bm_nl,
                             const float* __restrict__ Wu_nl,
                             const float* __restrict__ Wm_ln, const float* __restrict__ bm_ln,
                             const float* __restrict__ Wu_ln,
                             float* __restrict__ Wstack, float* __restrict__ bmp,
                             ushort_t* __restrict__ WbLin) {
    int idx = blockIdx.x * blockDim.x + threadIdx.x;
    const int per = 384 * H + H;
    int c = idx / per, r = idx % per;
    if (c >= 3) return;   // combo 3 (layer-2 node update) is dead code
    int l = c >> 1, rel = c & 1;
    const float* Wm = (rel ? Wm_ln : Wm_nl) + l * 256 * H;
    const float* Wu = (rel ? Wu_ln : Wu_nl) + l * 256 * H;
    const float* bm = (rel ? bm_ln : bm_nl) + l * H;
    float* Ws = Wstack + c * 384 * H;
    if (r < 384 * H) {
        int t = r / H, j = r % H;
        float val;
        if (t < 256) {
            float acc = 0.f;
            for (int k = 0; k < H; ++k) acc += Wm[t * H + k] * Wu[k * H + j];
            val = acc;
        } else {
            val = Wu[(t - 128) * H + j];
        }
        Ws[t * H + j] = val;
        if (c == 2) {
            WbLin[(size_t)(t >> 5) * 4096 + j * 32 + (t & 31)] = f2bf(val);
        }
    } else {
        int j = r - 384 * H;
        float acc = 0.f;
        for (int k = 0; k < H; ++k) acc += bm[k] * Wu[k * H + j];
        bmp[c * H + j] = acc;
    }
}

// ---------------- pass A: bucket-scatter edges by dst (128-dst buckets) ----------------
__launch_bounds__(256)
__global__ void bucket_scatter(const int* __restrict__ nl, const int* __restrict__ ln,
                               uint_t* __restrict__ bbuf, int* __restrict__ gcount) {
    int rel = blockIdx.y;
    const int* edge = rel ? ln : nl;
    uint_t* bb = bbuf + (size_t)rel * NB2 * BCAP2;
    int* gc = gcount + rel * NB2;
    __shared__ int hist[NB2], base[NB2], cur[NB2];
    int tid = threadIdx.x;
    for (int i = tid; i < NB2; i += 256) hist[i] = 0;
    __syncthreads();
    int e0 = blockIdx.x * 2048 + tid;
    int src[8], dst[8];
#pragma unroll
    for (int i = 0; i < 8; ++i) {
        int e = e0 + i * 256;
        if (e < NE) {
            src[i] = edge[e];
            dst[i] = edge[NE + e];
            atomicAdd(&hist[dst[i] >> 7], 1);
        } else dst[i] = -1;
    }
    __syncthreads();
    for (int i = tid; i < NB2; i += 256) { base[i] = atomicAdd(&gc[i], hist[i]); cur[i] = 0; }
    __syncthreads();
#pragma unroll
    for (int i = 0; i < 8; ++i) {
        if (dst[i] >= 0) {
            int b = dst[i] >> 7;
            int p = base[b] + atomicAdd(&cur[b], 1);
            bb[(size_t)b * BCAP2 + p] = (uint_t)src[i] | ((uint_t)(dst[i] & 127) << 16);
        }
    }
}

// ---------------- pass B: per-bucket S8 + degree via LDS (both relations) ----------------
// s8 LDS layout bank-rotated: col c of dst i lives at s8[i][(c+i)&7].
__launch_bounds__(256)
__global__ void bucket_deg_s8(const uint_t* __restrict__ bbuf, const int* __restrict__ gcount,
                              const float* __restrict__ x_node, const float* __restrict__ x_link,
                              float* __restrict__ S8l, float* __restrict__ S8n,
                              int* __restrict__ idl, int* __restrict__ idn) {
    int rel = blockIdx.y, b = blockIdx.x;
    int tid = threadIdx.x;
    const uint_t* bb = bbuf + ((size_t)rel * NB2 + b) * BCAP2;
    int n = gcount[rel * NB2 + b];
    const float* Xr = rel ? x_link : x_node;     // src-type raw features
    float* S8 = rel ? S8n : S8l;
    int* ideg = rel ? idn : idl;

    __shared__ int ld[128];
    __shared__ float s8[128][8];                 // 4 KB
    if (tid < 128) {
        ld[tid] = 0;
        *(float4*)&s8[tid][0] = make_float4(0.f, 0.f, 0.f, 0.f);
        *(float4*)&s8[tid][4] = make_float4(0.f, 0.f, 0.f, 0.f);
    }
    __syncthreads();

    // 2-unrolled entry loop for MLP
    for (int i = tid; i < n; i += 512) {
        uint_t v0 = bb[i];
        int i2 = i + 256;
        uint_t v1 = (i2 < n) ? bb[i2] : 0u;
        int d0 = v0 >> 16, s0 = (int)(v0 & 0xFFFFu);
        float4 a0 = *(const float4*)(Xr + (size_t)s0 * FR);
        float4 a1 = *(const float4*)(Xr + (size_t)s0 * FR + 4);
        float4 b0 = make_float4(0.f, 0.f, 0.f, 0.f), b1 = b0;
        int d1 = 0;
        if (i2 < n) {
            d1 = v1 >> 16;
            int s1 = (int)(v1 & 0xFFFFu);
            b0 = *(const float4*)(Xr + (size_t)s1 * FR);
            b1 = *(const float4*)(Xr + (size_t)s1 * FR + 4);
        }
        atomicAdd(&ld[d0], 1);
        float fa[8] = {a0.x, a0.y, a0.z, a0.w, a1.x, a1.y, a1.z, a1.w};
#pragma unroll
        for (int c = 0; c < 8; ++c)
            atomicAdd(&s8[d0][(c + d0) & 7], fa[c]);
        if (i2 < n) {
            atomicAdd(&ld[d1], 1);
            float fb[8] = {b0.x, b0.y, b0.z, b0.w, b1.x, b1.y, b1.z, b1.w};
#pragma unroll
            for (int c = 0; c < 8; ++c)
                atomicAdd(&s8[d1][(c + d1) & 7], fb[c]);
        }
    }
    __syncthreads();

    int dbase = b << 7;
    if (tid < 128) {
        int d = dbase + tid;
        if (d < NL) {
            ideg[d] = ld[tid];
            float o[8];
#pragma unroll
            for (int c = 0; c < 8; ++c) o[c] = s8[tid][(c + tid) & 7];
            *(float4*)(S8 + (size_t)d * FR)     = *(float4*)(o);
            *(float4*)(S8 + (size_t)d * FR + 4) = *(float4*)(o + 4);
        }
    }
}

// ---------------- gcount exclusive scan (link relation), 512 threads ----------------
__global__ void gscan(const int* __restrict__ gcount, int* __restrict__ bbase) {
    __shared__ int sh[512];
    int tid = threadIdx.x;
    int v0 = (tid < NB2) ? gcount[tid] : 0;
    sh[tid] = v0;
    __syncthreads();
    for (int d = 1; d < 512; d <<= 1) {
        int vv = (tid >= d) ? sh[tid - d] : 0;
        __syncthreads();
        sh[tid] += vv;
        __syncthreads();
    }
    if (tid < NB2) bbase[tid] = sh[tid] - v0;
}

// ---------------- link-only offset scan + CSR fill (128-dst buckets) ----------------
__launch_bounds__(256)
__global__ void scan_fill_l(const int* __restrict__ idl, const int* __restrict__ bbase,
                            int* __restrict__ offL,
                            const uint_t* __restrict__ bbuf, const int* __restrict__ gcount,
                            int* __restrict__ adjL) {
    int blk = blockIdx.x;
    const uint_t* bb = bbuf + (size_t)blk * BCAP2;   // rel 0 buckets
    int n = gcount[blk];

    __shared__ int sh[128];
    __shared__ int lcur[128];
    int tid = threadIdx.x;
    int dbase = blk << 7;
    int d0 = 0;
    if (tid < 128) {
        int d = dbase + tid;
        d0 = (d < NL) ? idl[d] : 0;
        sh[tid] = d0;
    }
    __syncthreads();
    for (int s = 1; s < 128; s <<= 1) {
        int vv = (tid >= s && tid < 128) ? sh[tid - s] : 0;
        __syncthreads();
        if (tid < 128) sh[tid] += vv;
        __syncthreads();
    }
    if (tid < 128) {
        int run = bbase[blk] + sh[tid] - d0;   // exclusive prefix
        lcur[tid] = run;
        int d = dbase + tid;
        if (d < NL) {
            offL[d] = run;
            if (d == NL - 1) offL[NL] = run + d0;
        }
    }
    __syncthreads();
    for (int i = tid; i < n; i += 256) {
        uint_t v = bb[i];
        int p = atomicAdd(&lcur[v >> 16], 1);
        adjL[p] = (int)(v & 0xFFFFu);
    }
}

// ---------------- layer-1: pure streaming GEMM (K=24), bf16 out ----------------
__launch_bounds__(256)
__global__ void gemm_l1(const float* __restrict__ S8l, const float* __restrict__ S8n,
                        const float* __restrict__ x_node, const float* __restrict__ x_link,
                        const int* __restrict__ idl, const int* __restrict__ idn,
                        const float* __restrict__ Wstack, const float* __restrict__ bmpAll,
                        const float* __restrict__ bu_nl, const float* __restrict__ bu_ln,
                        ushort_t* __restrict__ outl, ushort_t* __restrict__ outn) {
    int rel = blockIdx.y;
    const float* S8  = rel ? S8n : S8l;
    const float* Xo  = rel ? x_node : x_link;   // own raw features
    const int* ideg = rel ? idn : idl;
    const float* Ws  = Wstack + (size_t)rel * 384 * H;
    const float* bmp = bmpAll + rel * H;
    const float* bu  = rel ? bu_ln : bu_nl;
    ushort_t* Out = rel ? outn : outl;

    __shared__ float Wl[24][H];
    __shared__ float bf2s[2][H];
    int tid = threadIdx.x;
    for (int p = tid; p < 24 * H; p += 256) {
        int kk = p >> 7, c = p & 127;
        int srcrow = (kk >> 3) * 128 + (kk & 7);
        Wl[kk][c] = Ws[srcrow * H + c];
    }
    if (tid < 128) { bf2s[0][tid] = bmp[tid]; bf2s[1][tid] = bu[tid]; }
    __syncthreads();

    int rl = tid >> 4, t16 = tid & 15;
    int row = blockIdx.x * 16 + rl;              // grid 3125 -> exact
    float d = (float)ideg[row];
    float a[16];
    *(float4*)(a)      = *(const float4*)(S8 + (size_t)row * FR);
    *(float4*)(a + 4)  = *(const float4*)(S8 + (size_t)row * FR + 4);
    *(float4*)(a + 8)  = *(const float4*)(Xo + (size_t)row * FR);
    *(float4*)(a + 12) = *(const float4*)(Xo + (size_t)row * FR + 4);

    int c0 = t16 * 4, c1 = 64 + t16 * 4;
    float acc[8] = {};
#pragma unroll
    for (int k = 0; k < 8; ++k) {
        float4 w0 = *(const float4*)(&Wl[k][c0]);
        float4 w1 = *(const float4*)(&Wl[k][c1]);
        float av = a[k];
        acc[0] += av * w0.x; acc[1] += av * w0.y; acc[2] += av * w0.z; acc[3] += av * w0.w;
        acc[4] += av * w1.x; acc[5] += av * w1.y; acc[6] += av * w1.z; acc[7] += av * w1.w;
    }
#pragma unroll
    for (int k = 0; k < 8; ++k) {
        float4 w0 = *(const float4*)(&Wl[8 + k][c0]);
        float4 w1 = *(const float4*)(&Wl[8 + k][c1]);
        float av = d * a[8 + k];
        acc[0] += av * w0.x; acc[1] += av * w0.y; acc[2] += av * w0.z; acc[3] += av * w0.w;
        acc[4] += av * w1.x; acc[5] += av * w1.y; acc[6] += av * w1.z; acc[7] += av * w1.w;
    }
#pragma unroll
    for (int k = 0; k < 8; ++k) {
        float4 w0 = *(const float4*)(&Wl[16 + k][c0]);
        float4 w1 = *(const float4*)(&Wl[16 + k][c1]);
        float av = a[8 + k];
        acc[0] += av * w0.x; acc[1] += av * w0.y; acc[2] += av * w0.z; acc[3] += av * w0.w;
        acc[4] += av * w1.x; acc[5] += av * w1.y; acc[6] += av * w1.z; acc[7] += av * w1.w;
    }

    float o0[4], o1[4];
#pragma unroll
    for (int j = 0; j < 4; ++j) {
        o0[j] = fmaxf(acc[j]     + d * bf2s[0][c0 + j] + bf2s[1][c0 + j], 0.f);
        o1[j] = fmaxf(acc[j + 4] + d * bf2s[0][c1 + j] + bf2s[1][c1 + j], 0.f);
    }
    *(uint2*)(Out + (size_t)row * H + c0) = pk4(o0);
    *(uint2*)(Out + (size_t)row * H + c1) = pk4(o1);
}

// ---------------- layer-2: fused gather + MFMA GEMM + pooled epilogue (link only) ----------------
__launch_bounds__(256)
__global__ void gemm_mfma_pool(const int* __restrict__ offL, const int* __restrict__ adjL,
                               const ushort_t* __restrict__ xlb, const ushort_t* __restrict__ xnb,
                               const int* __restrict__ idl,
                               const ushort_t* __restrict__ WbLin, const float* __restrict__ bmpAll,
                               const float* __restrict__ bu_nl,
                               const int* __restrict__ batch, float* __restrict__ sums, int M) {
    const int* off = offL;
    const int* adj = adjL;
    const ushort_t* Xg = xnb;
    const ushort_t* Xo = xlb;
    const ushort_t* Wb = WbLin;
    const float* bmp = bmpAll + 2 * H;
    const float* bu  = bu_nl + H;

    __shared__ ushort_t T[TROWS * TSTR];   // 8.7 KB

    int tid = threadIdx.x;
    int lane = tid & 63;
    int wave = tid >> 6;
    int m0 = blockIdx.x * TROWS;
    int lrow = lane & 15, lg = lane >> 4;

    int trow = tid >> 3, chunk = tid & 7;
    int grow = m0 + trow;
    bool vr = grow < M;
    int cbase = chunk * 16;

    // ---- phase A: gather S (fp32 accum, 2-neighbor unroll) -> bf16 tile ----
    {
        float a[16];
#pragma unroll
        for (int j = 0; j < 16; ++j) a[j] = 0.f;
        if (vr) {
            int beg = off[grow], end = off[grow + 1];
            int i = beg;
            for (; i + 1 < end; i += 2) {
                const uint4* p0 = (const uint4*)(Xg + (size_t)adj[i] * H + cbase);
                const uint4* p1 = (const uint4*)(Xg + (size_t)adj[i + 1] * H + cbase);
                uint4 u0 = p0[0], u1 = p0[1];
                uint4 v0 = p1[0], v1 = p1[1];
                addpk8(a, u0); addpk8(a + 8, u1);
                addpk8(a, v0); addpk8(a + 8, v1);
            }
            if (i < end) {
                const uint4* p0 = (const uint4*)(Xg + (size_t)adj[i] * H + cbase);
                addpk8(a, p0[0]); addpk8(a + 8, p0[1]);
            }
        }
        uint4* dst = (uint4*)&T[trow * TSTR + cbase];
        uint4 w0, w1;
        unsigned* q0 = (unsigned*)&w0; unsigned* q1 = (unsigned*)&w1;
#pragma unroll
        for (int q = 0; q < 4; ++q) {
            q0[q] = (unsigned)f2bf(a[q * 2]) | ((unsigned)f2bf(a[q * 2 + 1]) << 16);
            q1[q] = (unsigned)f2bf(a[8 + q * 2]) | ((unsigned)f2bf(a[8 + q * 2 + 1]) << 16);
        }
        dst[0] = w0; dst[1] = w1;
    }

    f32x4 acc[2][2];
#pragma unroll
    for (int i = 0; i < 2; ++i)
#pragma unroll
        for (int j = 0; j < 2; ++j)
            acc[i][j] = (f32x4){0.f, 0.f, 0.f, 0.f};

    __syncthreads();
#pragma unroll
    for (int kk = 0; kk < 4; ++kk) {
        bf16x8 af[2], bfv[2];
#pragma unroll
        for (int mf = 0; mf < 2; ++mf)
            af[mf] = *(const bf16x8*)&T[(mf * 16 + lrow) * TSTR + kk * 32 + lg * 8];
#pragma unroll
        for (int nf = 0; nf < 2; ++nf)
            bfv[nf] = *(const bf16x8*)(Wb + (size_t)kk * 4096
                        + (wave * 32 + nf * 16 + lrow) * 32 + lg * 8);
#pragma unroll
        for (int mf = 0; mf < 2; ++mf)
#pragma unroll
            for (int nf = 0; nf < 2; ++nf)
                acc[mf][nf] = __builtin_amdgcn_mfma_f32_16x16x32_bf16(
                    af[mf], bfv[nf], acc[mf][nf], 0, 0, 0);
    }
    __syncthreads();

    // ---- phase B: own x row (stash) -> deg-scaled tile ----
    uint4 xs0, xs1;
    {
        if (vr) {
            const uint4* p = (const uint4*)(Xo + (size_t)grow * H + cbase);
            xs0 = p[0]; xs1 = p[1];
        } else {
            xs0 = xs1 = make_uint4(0u, 0u, 0u, 0u);
        }
        float dr = vr ? (float)idl[grow] : 0.f;
        uint4 w0 = xs0, w1 = xs1;
        unsigned* wp0 = (unsigned*)&w0;
        unsigned* wp1 = (unsigned*)&w1;
#pragma unroll
        for (int q = 0; q < 4; ++q) {
            float v0 = dr * bf2f((ushort_t)(wp0[q] & 0xFFFF));
            float v1 = dr * bf2f((ushort_t)(wp0[q] >> 16));
            wp0[q] = (unsigned)f2bf(v0) | ((unsigned)f2bf(v1) << 16);
            float v2 = dr * bf2f((ushort_t)(wp1[q] & 0xFFFF));
            float v3 = dr * bf2f((ushort_t)(wp1[q] >> 16));
            wp1[q] = (unsigned)f2bf(v2) | ((unsigned)f2bf(v3) << 16);
        }
        uint4* dst = (uint4*)&T[trow * TSTR + cbase];
        dst[0] = w0; dst[1] = w1;
    }
    __syncthreads();
#pragma unroll
    for (int kk = 0; kk < 4; ++kk) {
        bf16x8 af[2], bfv[2];
#pragma unroll
        for (int mf = 0; mf < 2; ++mf)
            af[mf] = *(const bf16x8*)&T[(mf * 16 + lrow) * TSTR + kk * 32 + lg * 8];
#pragma unroll
        for (int nf = 0; nf < 2; ++nf)
            bfv[nf] = *(const bf16x8*)(Wb + (size_t)(4 + kk) * 4096
                        + (wave * 32 + nf * 16 + lrow) * 32 + lg * 8);
#pragma unroll
        for (int mf = 0; mf < 2; ++mf)
#pragma unroll
            for (int nf = 0; nf < 2; ++nf)
                acc[mf][nf] = __builtin_amdgcn_mfma_f32_16x16x32_bf16(
                    af[mf], bfv[nf], acc[mf][nf], 0, 0, 0);
    }
    __syncthreads();

    // ---- phase C: unscaled x tile (from stash) ----
    {
        uint4* dst = (uint4*)&T[trow * TSTR + cbase];
        dst[0] = xs0; dst[1] = xs1;
    }
    __syncthreads();
#pragma unroll
    for (int kk = 0; kk < 4; ++kk) {
        bf16x8 af[2], bfv[2];
#pragma unroll
        for (int mf = 0; mf < 2; ++mf)
            af[mf] = *(const bf16x8*)&T[(mf * 16 + lrow) * TSTR + kk * 32 + lg * 8];
#pragma unroll
        for (int nf = 0; nf < 2; ++nf)
            bfv[nf] = *(const bf16x8*)(Wb + (size_t)(8 + kk) * 4096
                        + (wave * 32 + nf * 16 + lrow) * 32 + lg * 8);
#pragma unroll
        for (int mf = 0; mf < 2; ++mf)
#pragma unroll
            for (int nf = 0; nf < 2; ++nf)
                acc[mf][nf] = __builtin_amdgcn_mfma_f32_16x16x32_bf16(
                    af[mf], bfv[nf], acc[mf][nf], 0, 0, 0);
    }

    // ---- epilogue: bias + relu + fused mean-pool ----
    float bmpv[2], buv[2];
#pragma unroll
    for (int nf = 0; nf < 2; ++nf) {
        int col = wave * 32 + nf * 16 + lrow;
        bmpv[nf] = bmp[col];
        buv[nf] = bu[col];
    }
    int lastrow = min(m0 + TROWS, M) - 1;
    int g0 = batch[m0];
    int g1 = batch[lastrow];
    if (g0 == g1) {
        float ps0 = 0.f, ps1 = 0.f;
#pragma unroll
        for (int mf = 0; mf < 2; ++mf) {
#pragma unroll
            for (int r = 0; r < 4; ++r) {
                int row = m0 + mf * 16 + lg * 4 + r;
                if (row < M) {
                    float d = (float)idl[row];
                    ps0 += fmaxf(acc[mf][0][r] + d * bmpv[0] + buv[0], 0.f);
                    ps1 += fmaxf(acc[mf][1][r] + d * bmpv[1] + buv[1], 0.f);
                }
            }
        }
        ps0 += __shfl_xor(ps0, 16); ps0 += __shfl_xor(ps0, 32);
        ps1 += __shfl_xor(ps1, 16); ps1 += __shfl_xor(ps1, 32);
        if (lg == 0) {
            atomicAdd(&sums[g0 * H + wave * 32 + lrow], ps0);
            atomicAdd(&sums[g0 * H + wave * 32 + 16 + lrow], ps1);
        }
    } else {
#pragma unroll
        for (int mf = 0; mf < 2; ++mf) {
#pragma unroll
            for (int r = 0; r < 4; ++r) {
                int row = m0 + mf * 16 + lg * 4 + r;
                if (row < M) {
                    float d = (float)idl[row];
                    int g = batch[row];
                    float v0 = fmaxf(acc[mf][0][r] + d * bmpv[0] + buv[0], 0.f);
                    float v1 = fmaxf(acc[mf][1][r] + d * bmpv[1] + buv[1], 0.f);
                    atomicAdd(&sums[g * H + wave * 32 + lrow], v0);
                    atomicAdd(&sums[g * H + wave * 32 + 16 + lrow], v1);
                }
            }
        }
    }
}

// ---------------- pool finalize (counts via binary search) ----------------
__global__ void pool_final(const float* __restrict__ sums, const int* __restrict__ batch,
                           float* __restrict__ out) {
    int idx = blockIdx.x * blockDim.x + threadIdx.x;
    int g = idx / H;
    int lo = 0, hi = NL;
    while (lo < hi) { int mid = (lo + hi) >> 1; if (batch[mid] < g) lo = mid + 1; else hi = mid; }
    int first = lo;
    lo = 0; hi = NL;
    while (lo < hi) { int mid = (lo + hi) >> 1; if (batch[mid] < g + 1) lo = mid + 1; else hi = mid; }
    float cnt = (float)(lo - first);
    out[idx] = sums[idx] / fmaxf(cnt, 1.f);
}

static inline size_t rup(size_t n) { return (n + 15) & ~(size_t)15; }

extern "C" void kernel_launch(void* const* d_in, const int* in_sizes, int n_in,
                              void* d_out, int out_size, void* d_ws, size_t ws_size,
                              hipStream_t stream) {
    const float* x_node = (const float*)d_in[0];
    const float* x_link = (const float*)d_in[1];
    const float* Wm_nl  = (const float*)d_in[2];
    const float* bm_nl  = (const float*)d_in[3];
    const float* Wu_nl  = (const float*)d_in[4];
    const float* bu_nl  = (const float*)d_in[5];
    const float* Wm_ln  = (const float*)d_in[6];
    const float* bm_ln  = (const float*)d_in[7];
    const float* Wu_ln  = (const float*)d_in[8];
    const float* bu_ln  = (const float*)d_in[9];
    const int* nl_edge  = (const int*)d_in[10];
    const int* ln_edge  = (const int*)d_in[11];
    const int* batch_link = (const int*)d_in[12];
    (void)in_sizes; (void)n_in; (void)out_size; (void)ws_size;

    char* wsb = (char*)d_ws;
    size_t o = 0;
    auto alloc = [&](size_t elems) { void* p = wsb + o * 4; o += rup(elems); return p; };
    ushort_t* xnb  = (ushort_t*)alloc((size_t)NN * H / 2);
    ushort_t* xlb  = (ushort_t*)alloc((size_t)NL * H / 2);
    float* S8l   = (float*)alloc((size_t)NL * FR);
    float* S8n   = (float*)alloc((size_t)NN * FR);
    int*   idl   = (int*)alloc(NL);
    int*   idn   = (int*)alloc(NN);
    int*   offL  = (int*)alloc(NL + 1);
    int*   adjL  = (int*)alloc(NE);
    float* Wstack= (float*)alloc(3L * 384 * H);
    float* bmp   = (float*)alloc(4 * H);
    ushort_t* WbLin = (ushort_t*)alloc(12 * 4096 / 2);
    uint_t* bbuf  = (uint_t*)alloc((size_t)2 * NB2 * BCAP2);
    int*   bbase = (int*)alloc(NB2);
    // contiguous zero region: sums, gcount
    float* sums  = (float*)alloc(NG * H);    // 8192 (16-aligned)
    int*   gcount= (int*)alloc(2 * NB2);

    hipMemsetAsync(sums, 0, ((size_t)NG * H + rup(2 * NB2)) * 4, stream);

    precompute_w<<<(4 * (384 * H + H) + 255) / 256, 256, 0, stream>>>(
        Wm_nl, bm_nl, Wu_nl, Wm_ln, bm_ln, Wu_ln, Wstack, bmp, WbLin);

    // ---- bucketed aggregation + CSR build ----
    bucket_scatter<<<dim3((NE + 2047) / 2048, 2), 256, 0, stream>>>(
        nl_edge, ln_edge, bbuf, gcount);
    bucket_deg_s8<<<dim3(NB2, 2), 256, 0, stream>>>(
        bbuf, gcount, x_node, x_link, S8l, S8n, idl, idn);
    gscan<<<1, 512, 0, stream>>>(gcount, bbase);
    scan_fill_l<<<NB2, 256, 0, stream>>>(idl, bbase, offL, bbuf, gcount, adjL);

    // ---- layer 1 (pure streaming GEMM, both relations) ----
    gemm_l1<<<dim3(NL / 16, 2), 256, 0, stream>>>(
        S8l, S8n, x_node, x_link, idl, idn,
        Wstack, bmp, bu_nl, bu_ln, xlb, xnb);

    // ---- layer 2 (link only) + fused pool ----
    gemm_mfma_pool<<<(NL + TROWS - 1) / TROWS, 256, 0, stream>>>(
        offL, adjL, xlb, xnb, idl, WbLin, bmp, bu_nl,
        batch_link, sums, NL);

    pool_final<<<(NG * H) / 256, 256, 0, stream>>>(sums, batch_link, (float*)d_out);
}